// Round 19
// baseline (1063.115 us; speedup 1.0000x reference)
//
#include <hip/hip_runtime.h>
#include <math.h>

#define N_NODES  25000
#define N_EDGES  300000
#define N_GRAPHS 256
#define EMB_DIM  92
#define HID      256

typedef short bf16x8 __attribute__((ext_vector_type(8)));
typedef float f32x4  __attribute__((ext_vector_type(4)));

// fast softplus: max(x,0) + P5(exp(-|x|)) ; P5 = Hastings minimax ln(1+u) on [0,1], |err|<=1e-5
__device__ __forceinline__ float softplusf(float x){
    const float u = __expf(-fabsf(x));
    const float p = u*fmaf(u, fmaf(u, fmaf(u, fmaf(u, 0.03215845f, -0.13606275f),
                                            0.28947478f), -0.49190896f), 0.99949556f);
    return fmaxf(x, 0.0f) + p;
}
__device__ __forceinline__ unsigned short f2bf(float f){     // RNE
    unsigned int u = __float_as_uint(f);
    unsigned int r = (u + 0x7FFFu + ((u >> 16) & 1u)) >> 16;
    return (unsigned short)r;
}
__device__ __forceinline__ unsigned short f2bf_trunc(float f){
    return (unsigned short)(__float_as_uint(f) >> 16);
}
__device__ __forceinline__ float bf2f(unsigned short b){
    return __uint_as_float(((unsigned int)b) << 16);
}
__device__ __forceinline__ void split_bf(float h, unsigned short& hi, unsigned short& lo){
    const unsigned int u = __float_as_uint(h);
    hi = (unsigned short)(u >> 16);
    const float r = h - __uint_as_float(u & 0xFFFF0000u);
    lo = (unsigned short)(__float_as_uint(r) >> 16);
}
__device__ __forceinline__ int xcd_window(int nwin){
    const int per = (nwin + 7) >> 3;
    const int win = (blockIdx.x & 7) * per + (blockIdx.x >> 3);
    return (win < nwin) ? win : -1;
}

// ---------------------------------------------------------------- embedding gather + zero hist/gcnt/sums
__global__ void gather_emb_kernel(const int* __restrict__ atoms,
                                  const float* __restrict__ emb,
                                  float* __restrict__ x,
                                  int* __restrict__ hist, int* __restrict__ gcnt,
                                  float* __restrict__ sums)
{
    const int n = blockIdx.x;
    const int c = threadIdx.x;
    const int flat = n*128 + c;
    if (flat < N_NODES) hist[flat] = 0;
    if (flat < N_GRAPHS) gcnt[flat] = 0;
    if (flat < N_GRAPHS*HID) sums[flat] = 0.0f;
    if (c < EMB_DIM){
        const int a = atoms[n];
        x[(size_t)n*EMB_DIM + c] = emb[(size_t)a*EMB_DIM + c];
    }
}

// ---------------------------------------------------------------- hist: edge-dst histogram + batch (graph-size) histogram
__global__ __launch_bounds__(256) void hist_kernel(const int* __restrict__ dst, int* __restrict__ hist,
                                                   const int* __restrict__ batch, int* __restrict__ gcnt){
    const int e = blockIdx.x*256 + threadIdx.x;
    if (e < N_EDGES) atomicAdd(&hist[dst[e]], 1);
    if (e < N_NODES) atomicAdd(&gcnt[batch[e]], 1);
}

__global__ __launch_bounds__(1024) void scan_kernel(const int* __restrict__ hist, int* __restrict__ cursor){
    __shared__ int chunk[1024];
    const int t = threadIdx.x;
    const int base = t*25;                     // 1024*25 = 25600 >= 25000
    int local[25];
    int s = 0;
    #pragma unroll
    for (int i=0;i<25;i++){
        const int idx = base+i;
        const int v = (idx < N_NODES) ? hist[idx] : 0;
        local[i] = s; s += v;
    }
    chunk[t] = s;
    __syncthreads();
    for (int off=1; off<1024; off<<=1){
        int v = (t >= off) ? chunk[t-off] : 0;
        __syncthreads();
        chunk[t] += v;
        __syncthreads();
    }
    const int pre = (t > 0) ? chunk[t-1] : 0;
    #pragma unroll
    for (int i=0;i<25;i++){
        const int idx = base+i;
        if (idx < N_NODES) cursor[idx] = pre + local[i];
    }
}

// scatter + ea pre-gather + zero agg92 region (agg tail)
__global__ __launch_bounds__(256) void scatter_kernel(const int* __restrict__ src, const int* __restrict__ dst,
                                                      const float* __restrict__ ea,
                                                      int* __restrict__ cursor,
                                                      int* __restrict__ src_s, int* __restrict__ dst_s,
                                                      float* __restrict__ ea_s,
                                                      float* __restrict__ agg92){
    const int e = blockIdx.x*256 + threadIdx.x;
    if (e < N_EDGES){
        const int d = dst[e];
        const int pos = atomicAdd(&cursor[d], 1);
        src_s[pos] = src[e];
        dst_s[pos] = d;
        const float4 a = *(const float4*)(ea + (size_t)e*4);
        *(float4*)(ea_s + (size_t)pos*4) = a;
    }
    const int nth = gridDim.x*256;
    for (int i = blockIdx.x*256 + threadIdx.x; i < N_NODES*EMB_DIM; i += nth)
        agg92[i] = 0.0f;
}

// ---------------------------------------------------------------- merged weight packer (1 dispatch)
__device__ __forceinline__ void pack256_dev(const float* w, unsigned short* whi, int f){
    const int layer = f >> 7;
    const int rem   = f & 127;
    const int ntile = rem >> 3;
    const int k8    = rem & 7;
    for (int i = threadIdx.x; i < 512; i += 256){
        const int lane = i >> 3, j = i & 7;
        const int k = k8*32 + (lane >> 4)*8 + j;
        const int n = ntile*16 + (lane & 15);
        whi[(size_t)f*512 + i] = f2bf(w[(size_t)layer*HID*HID + (size_t)k*HID + n]);
    }
}
__device__ __forceinline__ void packpad_dev(const float* w, int Kin, int Nin, int ldn,
                                            unsigned short* whi, int f){
    const int k8 = f % 3;
    const int ntile = f / 3;
    for (int i = threadIdx.x; i < 512; i += 256){
        const int lane = i >> 3, j = i & 7;
        const int k = k8*32 + (lane >> 4)*8 + j;
        const int n = ntile*16 + (lane & 15);
        float v = 0.0f;
        if (k < Kin && n < Nin) v = w[(size_t)k*ldn + n];
        whi[(size_t)f*512 + i] = f2bf(v);
    }
}
__global__ __launch_bounds__(256) void pack_all_kernel(
    const float* __restrict__ ew2, const float* __restrict__ nw,
    const float* __restrict__ ew2_0, const float* __restrict__ nw_0,
    unsigned short* whi,
    unsigned short* nwhi,
    unsigned short* w92hi,
    unsigned short* nw92hi)
{
    const int b = blockIdx.x;                    // 834 blocks
    if (b < 384)      pack256_dev(ew2, whi, b);
    else if (b < 768) pack256_dev(nw, nwhi, b-384);
    else if (b < 786) packpad_dev(ew2_0, EMB_DIM, EMB_DIM, EMB_DIM, w92hi, b-768);
    else              packpad_dev(nw_0, EMB_DIM, HID, HID, nw92hi, b-786);
}

// ---------------------------------------------------------------- layer-0 edge conv MFMA (C=92, pad 96), 64 edges/block, single-RNE B
__global__ __launch_bounds__(256, 4) void edge_conv92_mfma_kernel(
    const int* __restrict__ src_s, const int* __restrict__ dst_s,
    const float* __restrict__ ea_s,
    const float* __restrict__ w1, const float* __restrict__ b1,
    const unsigned short* __restrict__ whi,          // 18 frags
    const float* __restrict__ b2,
    const float* __restrict__ x92, float* __restrict__ agg92)
{
    constexpr int C = EMB_DIM;     // 92
    constexpr int KP = 96;
    constexpr int LDA = 104;
    constexpr int EPB = 64;
    constexpr int NWIN = (N_EDGES + EPB - 1) / EPB;   // 4688
    __shared__ unsigned short aHi[EPB][LDA];   // 13.3 KB
    __shared__ float eaS[EPB][4];
    __shared__ int   srcS[EPB];
    __shared__ int   dstS[EPB];

    const int win = xcd_window(NWIN);
    if (win < 0) return;
    const int e0  = win * EPB;
    const int tid = threadIdx.x;

    {
        const int e = tid >> 2, comp = tid & 3;
        const int eid = min(e0 + e, N_EDGES-1);
        eaS[e][comp] = ea_s[(size_t)eid*4 + comp];
        if (tid < EPB){
            const int eid2 = min(e0 + tid, N_EDGES-1);
            srcS[tid] = src_s[eid2];
            dstS[tid] = dst_s[eid2];
        }
    }
    __syncthreads();

    // prefetch epilogue x-gathers (overlap with phase 1 + MFMA)
    const int lane = tid & 63, wv = tid >> 6;
    const int quad = lane >> 4, fcol = lane & 15;
    const int mpair = wv >> 1;
    const int ngrp  = wv & 1;
    int ncol[3];
    #pragma unroll
    for (int t=0;t<3;t++) ncol[t] = (ngrp*3 + t)*16 + fcol;
    const int ebase = mpair*32 + quad*8;
    float xv[8][3];
    #pragma unroll
    for (int j=0;j<8;j++){
        const int s = srcS[ebase + j];
        const bool valid = (e0 + ebase + j) < N_EDGES;
        #pragma unroll
        for (int t=0;t<3;t++)
            xv[j][t] = (valid && ncol[t] < C) ? x92[(size_t)s*C + ncol[t]] : 0.0f;
    }

    for (int idx = tid; idx < EPB*KP; idx += 256){
        const int e = idx / KP, k = idx - e*KP;
        float h = 0.0f;
        if (k < C){
            const float4 a = *(const float4*)&eaS[e][0];
            h = softplusf(fmaf(a.x, w1[k], fmaf(a.y, w1[C+k],
                          fmaf(a.z, w1[2*C+k], fmaf(a.w, w1[3*C+k], b1[k])))));
        }
        const int row = (e>>5)*32 + ((e>>2)&1)*16 + ((e>>3)&3)*4 + (e&3);
        aHi[row][k] = f2bf_trunc(h);
    }
    __syncthreads();

    f32x4 acc[2][3];
    #pragma unroll
    for (int m=0;m<2;m++)
        #pragma unroll
        for (int t=0;t<3;t++)
            #pragma unroll
            for (int j=0;j<4;j++) acc[m][t][j] = 0.0f;

    for (int k8=0;k8<3;k8++){
        bf16x8 ah[2];
        #pragma unroll
        for (int m=0;m<2;m++)
            ah[m] = *(const bf16x8*)(&aHi[mpair*32 + m*16 + fcol][0] + k8*32 + quad*8);
        #pragma unroll
        for (int t=0;t<3;t++){
            const int fi = (ngrp*3 + t)*3 + k8;
            const bf16x8 bh = *(const bf16x8*)(whi + (size_t)fi*512 + lane*8);
            #pragma unroll
            for (int m=0;m<2;m++)
                acc[m][t] = __builtin_amdgcn_mfma_f32_16x16x32_bf16(ah[m], bh, acc[m][t], 0, 0, 0);
        }
    }

    float bb[3];
    #pragma unroll
    for (int t=0;t<3;t++) bb[t] = (ncol[t] < C) ? b2[ncol[t]] : 0.0f;

    int dprev = dstS[ebase];
    float run[3] = {0.f,0.f,0.f};
    #pragma unroll
    for (int j=0;j<8;j++){
        const int d = dstS[ebase + j];
        if (d != dprev){
            #pragma unroll
            for (int t=0;t<3;t++){
                if (ncol[t] < C) atomicAdd(&agg92[(size_t)dprev*C + ncol[t]], run[t]);
                run[t] = 0.0f;
            }
            dprev = d;
        }
        #pragma unroll
        for (int t=0;t<3;t++)
            run[t] += (acc[j>>2][t][j&3] + bb[t]) * xv[j][t];
    }
    #pragma unroll
    for (int t=0;t<3;t++)
        if (ncol[t] < C) atomicAdd(&agg92[(size_t)dprev*C + ncol[t]], run[t]);
}

// ---------------------------------------------------------------- node update 92->256 MFMA; 2-MFMA scheme (A hi/lo x B-RNE); zeroes agg
__global__ __launch_bounds__(256) void node_update92_mfma_kernel(
    float* __restrict__ agg92,          // = agg + N*164 (aliased tail)
    float* __restrict__ aggfull,        // full [N,256] buffer, zero prefix [0, N*164)
    const unsigned short* __restrict__ whi,          // 48 frags
    const float* __restrict__ b, float* __restrict__ xout)
{
    constexpr int C = EMB_DIM;
    constexpr int KP = 96;
    constexpr int LDA = 104;
    __shared__ unsigned short aHi[16][LDA];
    __shared__ unsigned short aLo[16][LDA];

    const int n0  = blockIdx.x * 16;
    const int tid = threadIdx.x;

    for (int idx = tid; idx < 16*KP; idx += 256){
        const int i = idx / KP, k = idx - i*KP;
        const int node = n0 + i;
        float v = 0.0f;
        if (k < C && node < N_NODES){
            v = agg92[(size_t)node*C + k];
            agg92[(size_t)node*C + k] = 0.0f;
        }
        unsigned short hb, lb;
        split_bf(v, hb, lb);
        aHi[i][k] = hb;
        aLo[i][k] = lb;
    }
    __syncthreads();

    const int lane = tid & 63, wv = tid >> 6;
    const int quad = lane >> 4, fcol = lane & 15;

    f32x4 acc[4];
    #pragma unroll
    for (int t=0;t<4;t++)
        #pragma unroll
        for (int j=0;j<4;j++) acc[t][j] = 0.0f;

    const unsigned short* aHrow = &aHi[fcol][0];
    const unsigned short* aLrow = &aLo[fcol][0];

    for (int k8=0;k8<3;k8++){
        const bf16x8 ah = *(const bf16x8*)(aHrow + k8*32 + quad*8);
        const bf16x8 al = *(const bf16x8*)(aLrow + k8*32 + quad*8);
        #pragma unroll
        for (int t=0;t<4;t++){
            const int fi = (wv*4 + t)*3 + k8;
            const bf16x8 bh = *(const bf16x8*)(whi + (size_t)fi*512 + lane*8);
            acc[t] = __builtin_amdgcn_mfma_f32_16x16x32_bf16(ah, bh, acc[t], 0, 0, 0);
            acc[t] = __builtin_amdgcn_mfma_f32_16x16x32_bf16(al, bh, acc[t], 0, 0, 0);
        }
    }

    #pragma unroll
    for (int i=0;i<4;i++){
        const int node = n0 + quad*4 + i;
        if (node < N_NODES){
            #pragma unroll
            for (int t=0;t<4;t++){
                const int n = (wv*4 + t)*16 + fcol;
                xout[(size_t)node*HID + n] = softplusf(acc[t][i] + b[n]);
            }
        }
    }

    const int nth = gridDim.x*256;
    for (int idx = blockIdx.x*256 + tid; idx < N_NODES*164; idx += nth)
        aggfull[idx] = 0.0f;
}

// ---------------------------------------------------------------- layers 1-3 edge conv, MFMA, 64 edges/block, 512 threads (8 waves)
// x-gathers issued BETWEEN phase 1 and the MFMA loop: latency overlaps MFMA,
// registers live only across the MFMA loop (not across phase-1 softplus).
__global__ __launch_bounds__(512, 6) void edge_conv256_mfma_kernel(
    const int* __restrict__ src_s, const int* __restrict__ dst_s,
    const float* __restrict__ ea_s,
    const float* __restrict__ w1, const float* __restrict__ b1,
    const unsigned short* __restrict__ whi,
    const float* __restrict__ b2,
    const float* __restrict__ x, float* __restrict__ agg)
{
    constexpr int C = HID;
    constexpr int LDA = C + 8;                 // 528 B row stride
    constexpr int EPB = 64;
    constexpr int NWIN = (N_EDGES + EPB - 1) / EPB;   // 4688
    __shared__ unsigned short aHi[EPB][LDA];   // 33.8 KB
    __shared__ float eaS[EPB][4];
    __shared__ int   srcS[EPB];
    __shared__ int   dstS[EPB];

    const int win = xcd_window(NWIN);
    if (win < 0) return;
    const int e0  = win * EPB;
    const int tid = threadIdx.x;

    if (tid < 256){
        const int e = tid >> 2, comp = tid & 3;
        const int eid = min(e0 + e, N_EDGES-1);
        eaS[e][comp] = ea_s[(size_t)eid*4 + comp];
    } else if (tid < 320){
        const int e = tid - 256;
        srcS[e] = src_s[min(e0 + e, N_EDGES-1)];
    } else if (tid < 384){
        const int e = tid - 320;
        dstS[e] = dst_s[min(e0 + e, N_EDGES-1)];
    }
    __syncthreads();

    // phase 1: h1 = softplus(ea@w1+b1) -> bf16 LDS rows (chain-permuted), 2 channels/thread
    {
        const int k2 = (tid & 127) * 2;
        const int g  = tid >> 7;               // 0..3: edges [g*16, g*16+16)
        const float wa0 = w1[k2],   wa1 = w1[C+k2],   wa2 = w1[2*C+k2],   wa3 = w1[3*C+k2];
        const float wb0 = w1[k2+1], wb1 = w1[C+k2+1], wb2 = w1[2*C+k2+1], wb3 = w1[3*C+k2+1];
        const float bk0 = b1[k2], bk1 = b1[k2+1];
        #pragma unroll
        for (int ii=0; ii<16; ii++){
            const int e = g*16 + ii;
            const float4 a = *(const float4*)&eaS[e][0];
            const float v0 = fmaf(a.x,wa0,fmaf(a.y,wa1,fmaf(a.z,wa2,fmaf(a.w,wa3,bk0))));
            const float v1 = fmaf(a.x,wb0,fmaf(a.y,wb1,fmaf(a.z,wb2,fmaf(a.w,wb3,bk1))));
            const unsigned int packed = (unsigned int)f2bf_trunc(softplusf(v0))
                                      | ((unsigned int)f2bf_trunc(softplusf(v1)) << 16);
            const int q = e >> 4, j = e & 15;
            *(unsigned int*)&aHi[(j>>2)*16 + q*4 + (j&3)][k2] = packed;
        }
    }
    __syncthreads();

    const int lane = tid & 63, wv = tid >> 6;  // 8 waves
    const int quad = lane >> 4, fcol = lane & 15;

    // issue x-gathers NOW: latency overlaps the MFMA loop below
    const int ebase = quad*16;
    float xv[16][2];
    #pragma unroll
    for (int j=0;j<16;j++){
        const int s = srcS[ebase + j];
        const bool valid = (e0 + ebase + j) < N_EDGES;
        #pragma unroll
        for (int t=0;t<2;t++)
            xv[j][t] = valid ? x[(size_t)s*C + (wv*2 + t)*16 + fcol] : 0.0f;
    }

    f32x4 acc[4][2];     // [m-tile][n-tile]
    #pragma unroll
    for (int m=0;m<4;m++)
        #pragma unroll
        for (int t=0;t<2;t++)
            #pragma unroll
            for (int j=0;j<4;j++) acc[m][t][j] = 0.0f;

    for (int k8=0;k8<8;k8++){
        bf16x8 ah[4];
        #pragma unroll
        for (int m=0;m<4;m++)
            ah[m] = *(const bf16x8*)(&aHi[m*16 + fcol][0] + k8*32 + quad*8);
        #pragma unroll
        for (int t=0;t<2;t++){
            const int fi = (wv*2 + t)*8 + k8;
            const bf16x8 bh = *(const bf16x8*)(whi + (size_t)fi*512 + lane*8);
            #pragma unroll
            for (int m=0;m<4;m++)
                acc[m][t] = __builtin_amdgcn_mfma_f32_16x16x32_bf16(ah[m], bh, acc[m][t], 0, 0, 0);
        }
    }

    float bb[2];
    #pragma unroll
    for (int t=0;t<2;t++) bb[t] = b2[(wv*2 + t)*16 + fcol];

    int dprev = dstS[ebase];
    float run[2] = {0.f,0.f};
    #pragma unroll
    for (int j=0;j<16;j++){
        const int d = dstS[ebase + j];
        if (d != dprev){
            #pragma unroll
            for (int t=0;t<2;t++){
                atomicAdd(&agg[(size_t)dprev*C + (wv*2 + t)*16 + fcol], run[t]);
                run[t] = 0.0f;
            }
            dprev = d;
        }
        #pragma unroll
        for (int t=0;t<2;t++)
            run[t] += (acc[j>>2][t][j&3] + bb[t]) * xv[j][t];
    }
    #pragma unroll
    for (int t=0;t<2;t++)
        atomicAdd(&agg[(size_t)dprev*C + (wv*2 + t)*16 + fcol], run[t]);
}

// ---------------------------------------------------------------- node update MFMA (CIN=256); 2-MFMA scheme; optional zeroing; optional fused pool
__global__ __launch_bounds__(256) void node_update_mfma_kernel(
    float* __restrict__ agg,
    const unsigned short* __restrict__ whi,
    const float* __restrict__ b, float* __restrict__ xout, int zero_agg,
    const int* __restrict__ batch, float* __restrict__ sums, int do_pool)
{
    constexpr int C = HID;
    constexpr int LDA = C + 8;
    __shared__ unsigned short aHi[16][LDA];
    __shared__ unsigned short aLo[16][LDA];
    __shared__ int batchS[16];

    const int n0  = blockIdx.x * 16;
    const int tid = threadIdx.x;

    if (tid < 16) batchS[tid] = batch[min(n0 + tid, N_NODES-1)];

    #pragma unroll
    for (int it=0; it<16; it++){
        const int node = n0 + it;
        float v = 0.0f;
        if (node < N_NODES){
            v = agg[(size_t)node*C + tid];
            if (zero_agg) agg[(size_t)node*C + tid] = 0.0f;
        }
        unsigned short hb, lb;
        split_bf(v, hb, lb);
        aHi[it][tid] = hb;
        aLo[it][tid] = lb;
    }
    __syncthreads();

    const int lane = tid & 63, wv = tid >> 6;
    const int quad = lane >> 4, fcol = lane & 15;

    f32x4 acc[4];
    #pragma unroll
    for (int t=0;t<4;t++)
        #pragma unroll
        for (int j=0;j<4;j++) acc[t][j] = 0.0f;

    const unsigned short* aHrow = &aHi[fcol][0];
    const unsigned short* aLrow = &aLo[fcol][0];

    for (int k8=0;k8<8;k8++){
        const bf16x8 ah = *(const bf16x8*)(aHrow + k8*32 + quad*8);
        const bf16x8 al = *(const bf16x8*)(aLrow + k8*32 + quad*8);
        #pragma unroll
        for (int t=0;t<4;t++){
            const int fi = (wv*4 + t)*8 + k8;
            const bf16x8 bh = *(const bf16x8*)(whi + (size_t)fi*512 + lane*8);
            acc[t] = __builtin_amdgcn_mfma_f32_16x16x32_bf16(ah, bh, acc[t], 0, 0, 0);
            acc[t] = __builtin_amdgcn_mfma_f32_16x16x32_bf16(al, bh, acc[t], 0, 0, 0);
        }
    }

    float vals[4][4];
    #pragma unroll
    for (int i=0;i<4;i++){
        const int node = n0 + quad*4 + i;
        #pragma unroll
        for (int t=0;t<4;t++){
            float v = 0.0f;
            if (node < N_NODES){
                const int n = (wv*4 + t)*16 + fcol;
                v = softplusf(acc[t][i] + b[n]);
                xout[(size_t)node*C + n] = v;
            }
            vals[i][t] = v;
        }
    }

    if (do_pool){
        int gprev = batchS[quad*4];
        float run[4] = {0.f,0.f,0.f,0.f};
        #pragma unroll
        for (int i=0;i<4;i++){
            const int g = batchS[quad*4 + i];
            if (g != gprev){
                #pragma unroll
                for (int t=0;t<4;t++){
                    atomicAdd(&sums[(size_t)gprev*HID + (wv*4+t)*16 + fcol], run[t]);
                    run[t] = 0.0f;
                }
                gprev = g;
            }
            #pragma unroll
            for (int t=0;t<4;t++) run[t] += vals[i][t];
        }
        #pragma unroll
        for (int t=0;t<4;t++)
            atomicAdd(&sums[(size_t)gprev*HID + (wv*4+t)*16 + fcol], run[t]);
    }
}

// ---------------------------------------------------------------- readout MLP (one block per graph)
__global__ __launch_bounds__(256) void readout_kernel(
    const float* __restrict__ sums, const int* __restrict__ gcnt,
    const float* __restrict__ rw1, const float* __restrict__ rb1,
    const float* __restrict__ rw2, const float* __restrict__ rb2,
    const float* __restrict__ rw3, const float* __restrict__ rb3,
    float* __restrict__ out)
{
    __shared__ float g[HID];
    __shared__ float h[HID];
    __shared__ float h2[HID/2];
    __shared__ float red[256];
    const int gi = blockIdx.x;
    const int t  = threadIdx.x;
    const float cnt = fmaxf((float)gcnt[gi], 1.0f);
    g[t] = sums[(size_t)gi*HID + t] / cnt;
    __syncthreads();
    float acc = rb1[t];
    for (int k=0;k<HID;k++) acc = fmaf(g[k], rw1[(size_t)k*HID + t], acc);
    h[t] = softplusf(acc);
    __syncthreads();
    if (t < HID/2){
        float a2 = rb2[t];
        for (int k=0;k<HID;k++) a2 = fmaf(h[k], rw2[(size_t)k*(HID/2) + t], a2);
        h2[t] = softplusf(a2);
    }
    __syncthreads();
    red[t] = (t < HID/2) ? h2[t]*rw3[t] : 0.0f;
    __syncthreads();
    for (int s2=128; s2>0; s2>>=1){
        if (t < s2) red[t] += red[t+s2];
        __syncthreads();
    }
    if (t == 0) out[gi] = red[0] + rb3[0];
}

// ---------------------------------------------------------------- launcher
extern "C" void kernel_launch(void* const* d_in, const int* in_sizes, int n_in,
                              void* d_out, int out_size, void* d_ws, size_t ws_size,
                              hipStream_t stream)
{
    const int*   x_atoms = (const int*)d_in[0];
    const int*   eidx    = (const int*)d_in[1];
    const int*   src     = eidx;               // edge_index[0]
    const int*   dst     = eidx + N_EDGES;     // edge_index[1]
    const float* ea      = (const float*)d_in[2];
    const int*   batch   = (const int*)d_in[3];
    const float* emb     = (const float*)d_in[4];
    const float* ew1_0   = (const float*)d_in[5];
    const float* eb1_0   = (const float*)d_in[6];
    const float* ew2_0   = (const float*)d_in[7];
    const float* eb2_0   = (const float*)d_in[8];
    const float* nw_0    = (const float*)d_in[9];
    const float* nb_0    = (const float*)d_in[10];
    const float* ew1     = (const float*)d_in[11];
    const float* eb1     = (const float*)d_in[12];
    const float* ew2     = (const float*)d_in[13];
    const float* eb2     = (const float*)d_in[14];
    const float* nw      = (const float*)d_in[15];
    const float* nb      = (const float*)d_in[16];
    const float* rw1     = (const float*)d_in[17];
    const float* rb1     = (const float*)d_in[18];
    const float* rw2     = (const float*)d_in[19];
    const float* rb2     = (const float*)d_in[20];
    const float* rw3     = (const float*)d_in[21];
    const float* rb3     = (const float*)d_in[22];
    float* out = (float*)d_out;

    float* x    = (float*)d_ws;
    float* agg  = x   + (size_t)N_NODES*HID;
    float* agg92 = agg + (size_t)N_NODES*164;          // aliased tail of agg ([N,92] region)
    float* sums = agg + (size_t)N_NODES*HID;
    unsigned short* whi  = (unsigned short*)(sums + (size_t)N_GRAPHS*HID);
    unsigned short* nwhi = whi  + (size_t)3*128*512;
    unsigned short* w92hi  = nwhi + (size_t)3*128*512;    // 18 frags
    unsigned short* nw92hi = w92hi + (size_t)18*512;      // 48 frags
    float* ea_s = (float*)(nw92hi + (size_t)48*512);      // [E,4] sorted edge attrs
    int* hist   = (int*)(ea_s + (size_t)N_EDGES*4);
    int* gcnt   = hist   + N_NODES;                       // [256] graph sizes
    int* cursor = gcnt   + N_GRAPHS;
    int* src_s  = cursor + N_NODES;
    int* dst_s  = src_s  + N_EDGES;

    const int NWIN64 = (N_EDGES + 63) / 64;           // 4688 (divisible by 8)

    // 1. embedding gather + zero hist/gcnt/sums
    hipLaunchKernelGGL(gather_emb_kernel, dim3(N_NODES), dim3(128), 0, stream,
                       x_atoms, emb, x, hist, gcnt, sums);
    // 2-4. counting sort by dst (+ graph sizes, + zero agg92 region)
    hipLaunchKernelGGL(hist_kernel, dim3((N_EDGES+255)/256), dim3(256), 0, stream, dst, hist, batch, gcnt);
    hipLaunchKernelGGL(scan_kernel, dim3(1), dim3(1024), 0, stream, hist, cursor);
    hipLaunchKernelGGL(scatter_kernel, dim3((N_EDGES+255)/256), dim3(256), 0, stream,
                       src, dst, ea, cursor, src_s, dst_s, ea_s, agg92);
    // 5. pack all weights (hi only — 2-MFMA schemes everywhere)
    hipLaunchKernelGGL(pack_all_kernel, dim3(834), dim3(256), 0, stream,
                       ew2, nw, ew2_0, nw_0,
                       whi, nwhi, w92hi, nw92hi);

    // 6-7. layer 0
    hipLaunchKernelGGL(edge_conv92_mfma_kernel, dim3((NWIN64+7)/8*8), dim3(256), 0, stream,
                       src_s, dst_s, ea_s, ew1_0, eb1_0, w92hi, eb2_0, x, agg92);
    hipLaunchKernelGGL(node_update92_mfma_kernel, dim3((N_NODES+15)/16), dim3(256), 0, stream,
                       agg92, agg, nw92hi, nb_0, x);

    // 8-10. layers 1..3
    for (int i=0;i<3;i++){
        hipLaunchKernelGGL(edge_conv256_mfma_kernel, dim3((NWIN64+7)/8*8), dim3(512), 0, stream,
                           src_s, dst_s, ea_s,
                           ew1 + (size_t)i*4*HID, eb1 + (size_t)i*HID,
                           whi + (size_t)i*128*512,
                           eb2 + (size_t)i*HID,
                           x, agg);
        hipLaunchKernelGGL(node_update_mfma_kernel, dim3((N_NODES+15)/16), dim3(256), 0, stream,
                           agg, nwhi + (size_t)i*128*512,
                           nb + (size_t)i*HID, x, (i < 2) ? 1 : 0,
                           batch, sums, (i == 2) ? 1 : 0);
    }

    // 11. readout
    hipLaunchKernelGGL(readout_kernel, dim3(N_GRAPHS), dim3(256), 0, stream,
                       sums, gcnt, rw1, rb1, rw2, rb2, rw3, rb3, out);
}

// Round 20
// 615.893 us; speedup vs baseline: 1.7261x; 1.7261x over previous
//
#include <hip/hip_runtime.h>
#include <math.h>

#define N_NODES  25000
#define N_EDGES  300000
#define N_GRAPHS 256
#define EMB_DIM  92
#define HID      256

typedef short bf16x8 __attribute__((ext_vector_type(8)));
typedef float f32x4  __attribute__((ext_vector_type(4)));

// fast softplus: max(x,0) + P5(exp(-|x|)) ; P5 = Hastings minimax ln(1+u) on [0,1], |err|<=1e-5
__device__ __forceinline__ float softplusf(float x){
    const float u = __expf(-fabsf(x));
    const float p = u*fmaf(u, fmaf(u, fmaf(u, fmaf(u, 0.03215845f, -0.13606275f),
                                            0.28947478f), -0.49190896f), 0.99949556f);
    return fmaxf(x, 0.0f) + p;
}
__device__ __forceinline__ unsigned short f2bf(float f){     // RNE
    unsigned int u = __float_as_uint(f);
    unsigned int r = (u + 0x7FFFu + ((u >> 16) & 1u)) >> 16;
    return (unsigned short)r;
}
__device__ __forceinline__ unsigned short f2bf_trunc(float f){
    return (unsigned short)(__float_as_uint(f) >> 16);
}
__device__ __forceinline__ float bf2f(unsigned short b){
    return __uint_as_float(((unsigned int)b) << 16);
}
__device__ __forceinline__ void split_bf(float h, unsigned short& hi, unsigned short& lo){
    const unsigned int u = __float_as_uint(h);
    hi = (unsigned short)(u >> 16);
    const float r = h - __uint_as_float(u & 0xFFFF0000u);
    lo = (unsigned short)(__float_as_uint(r) >> 16);
}
__device__ __forceinline__ int xcd_window(int nwin){
    const int per = (nwin + 7) >> 3;
    const int win = (blockIdx.x & 7) * per + (blockIdx.x >> 3);
    return (win < nwin) ? win : -1;
}

// ---------------------------------------------------------------- embedding gather + zero hist/gcnt/sums
__global__ void gather_emb_kernel(const int* __restrict__ atoms,
                                  const float* __restrict__ emb,
                                  float* __restrict__ x,
                                  int* __restrict__ hist, int* __restrict__ gcnt,
                                  float* __restrict__ sums)
{
    const int n = blockIdx.x;
    const int c = threadIdx.x;
    const int flat = n*128 + c;
    if (flat < N_NODES) hist[flat] = 0;
    if (flat < N_GRAPHS) gcnt[flat] = 0;
    if (flat < N_GRAPHS*HID) sums[flat] = 0.0f;
    if (c < EMB_DIM){
        const int a = atoms[n];
        x[(size_t)n*EMB_DIM + c] = emb[(size_t)a*EMB_DIM + c];
    }
}

// ---------------------------------------------------------------- hist: edge-dst histogram + batch (graph-size) histogram
__global__ __launch_bounds__(256) void hist_kernel(const int* __restrict__ dst, int* __restrict__ hist,
                                                   const int* __restrict__ batch, int* __restrict__ gcnt){
    const int e = blockIdx.x*256 + threadIdx.x;
    if (e < N_EDGES) atomicAdd(&hist[dst[e]], 1);
    if (e < N_NODES) atomicAdd(&gcnt[batch[e]], 1);
}

__global__ __launch_bounds__(1024) void scan_kernel(const int* __restrict__ hist, int* __restrict__ cursor){
    __shared__ int chunk[1024];
    const int t = threadIdx.x;
    const int base = t*25;                     // 1024*25 = 25600 >= 25000
    int local[25];
    int s = 0;
    #pragma unroll
    for (int i=0;i<25;i++){
        const int idx = base+i;
        const int v = (idx < N_NODES) ? hist[idx] : 0;
        local[i] = s; s += v;
    }
    chunk[t] = s;
    __syncthreads();
    for (int off=1; off<1024; off<<=1){
        int v = (t >= off) ? chunk[t-off] : 0;
        __syncthreads();
        chunk[t] += v;
        __syncthreads();
    }
    const int pre = (t > 0) ? chunk[t-1] : 0;
    #pragma unroll
    for (int i=0;i<25;i++){
        const int idx = base+i;
        if (idx < N_NODES) cursor[idx] = pre + local[i];
    }
}

// scatter + ea pre-gather + zero agg92 region (agg tail)
__global__ __launch_bounds__(256) void scatter_kernel(const int* __restrict__ src, const int* __restrict__ dst,
                                                      const float* __restrict__ ea,
                                                      int* __restrict__ cursor,
                                                      int* __restrict__ src_s, int* __restrict__ dst_s,
                                                      float* __restrict__ ea_s,
                                                      float* __restrict__ agg92){
    const int e = blockIdx.x*256 + threadIdx.x;
    if (e < N_EDGES){
        const int d = dst[e];
        const int pos = atomicAdd(&cursor[d], 1);
        src_s[pos] = src[e];
        dst_s[pos] = d;
        const float4 a = *(const float4*)(ea + (size_t)e*4);
        *(float4*)(ea_s + (size_t)pos*4) = a;
    }
    const int nth = gridDim.x*256;
    for (int i = blockIdx.x*256 + threadIdx.x; i < N_NODES*EMB_DIM; i += nth)
        agg92[i] = 0.0f;
}

// ---------------------------------------------------------------- merged weight packer (1 dispatch)
__device__ __forceinline__ void pack256_dev(const float* w, unsigned short* whi, int f){
    const int layer = f >> 7;
    const int rem   = f & 127;
    const int ntile = rem >> 3;
    const int k8    = rem & 7;
    for (int i = threadIdx.x; i < 512; i += 256){
        const int lane = i >> 3, j = i & 7;
        const int k = k8*32 + (lane >> 4)*8 + j;
        const int n = ntile*16 + (lane & 15);
        whi[(size_t)f*512 + i] = f2bf(w[(size_t)layer*HID*HID + (size_t)k*HID + n]);
    }
}
__device__ __forceinline__ void packpad_dev(const float* w, int Kin, int Nin, int ldn,
                                            unsigned short* whi, int f){
    const int k8 = f % 3;
    const int ntile = f / 3;
    for (int i = threadIdx.x; i < 512; i += 256){
        const int lane = i >> 3, j = i & 7;
        const int k = k8*32 + (lane >> 4)*8 + j;
        const int n = ntile*16 + (lane & 15);
        float v = 0.0f;
        if (k < Kin && n < Nin) v = w[(size_t)k*ldn + n];
        whi[(size_t)f*512 + i] = f2bf(v);
    }
}
__global__ __launch_bounds__(256) void pack_all_kernel(
    const float* __restrict__ ew2, const float* __restrict__ nw,
    const float* __restrict__ ew2_0, const float* __restrict__ nw_0,
    unsigned short* whi,
    unsigned short* nwhi,
    unsigned short* w92hi,
    unsigned short* nw92hi)
{
    const int b = blockIdx.x;                    // 834 blocks
    if (b < 384)      pack256_dev(ew2, whi, b);
    else if (b < 768) pack256_dev(nw, nwhi, b-384);
    else if (b < 786) packpad_dev(ew2_0, EMB_DIM, EMB_DIM, EMB_DIM, w92hi, b-768);
    else              packpad_dev(nw_0, EMB_DIM, HID, HID, nw92hi, b-786);
}

// ---------------------------------------------------------------- layer-0 edge conv MFMA (C=92, pad 96), 64 edges/block, single-RNE B
__global__ __launch_bounds__(256, 4) void edge_conv92_mfma_kernel(
    const int* __restrict__ src_s, const int* __restrict__ dst_s,
    const float* __restrict__ ea_s,
    const float* __restrict__ w1, const float* __restrict__ b1,
    const unsigned short* __restrict__ whi,          // 18 frags
    const float* __restrict__ b2,
    const float* __restrict__ x92, float* __restrict__ agg92)
{
    constexpr int C = EMB_DIM;     // 92
    constexpr int KP = 96;
    constexpr int LDA = 104;
    constexpr int EPB = 64;
    constexpr int NWIN = (N_EDGES + EPB - 1) / EPB;   // 4688
    __shared__ unsigned short aHi[EPB][LDA];   // 13.3 KB
    __shared__ float eaS[EPB][4];
    __shared__ int   srcS[EPB];
    __shared__ int   dstS[EPB];

    const int win = xcd_window(NWIN);
    if (win < 0) return;
    const int e0  = win * EPB;
    const int tid = threadIdx.x;

    {
        const int e = tid >> 2, comp = tid & 3;
        const int eid = min(e0 + e, N_EDGES-1);
        eaS[e][comp] = ea_s[(size_t)eid*4 + comp];
        if (tid < EPB){
            const int eid2 = min(e0 + tid, N_EDGES-1);
            srcS[tid] = src_s[eid2];
            dstS[tid] = dst_s[eid2];
        }
    }
    __syncthreads();

    // prefetch epilogue x-gathers (overlap with phase 1 + MFMA)
    const int lane = tid & 63, wv = tid >> 6;
    const int quad = lane >> 4, fcol = lane & 15;
    const int mpair = wv >> 1;
    const int ngrp  = wv & 1;
    int ncol[3];
    #pragma unroll
    for (int t=0;t<3;t++) ncol[t] = (ngrp*3 + t)*16 + fcol;
    const int ebase = mpair*32 + quad*8;
    float xv[8][3];
    #pragma unroll
    for (int j=0;j<8;j++){
        const int s = srcS[ebase + j];
        const bool valid = (e0 + ebase + j) < N_EDGES;
        #pragma unroll
        for (int t=0;t<3;t++)
            xv[j][t] = (valid && ncol[t] < C) ? x92[(size_t)s*C + ncol[t]] : 0.0f;
    }

    for (int idx = tid; idx < EPB*KP; idx += 256){
        const int e = idx / KP, k = idx - e*KP;
        float h = 0.0f;
        if (k < C){
            const float4 a = *(const float4*)&eaS[e][0];
            h = softplusf(fmaf(a.x, w1[k], fmaf(a.y, w1[C+k],
                          fmaf(a.z, w1[2*C+k], fmaf(a.w, w1[3*C+k], b1[k])))));
        }
        const int row = (e>>5)*32 + ((e>>2)&1)*16 + ((e>>3)&3)*4 + (e&3);
        aHi[row][k] = f2bf_trunc(h);
    }
    __syncthreads();

    f32x4 acc[2][3];
    #pragma unroll
    for (int m=0;m<2;m++)
        #pragma unroll
        for (int t=0;t<3;t++)
            #pragma unroll
            for (int j=0;j<4;j++) acc[m][t][j] = 0.0f;

    for (int k8=0;k8<3;k8++){
        bf16x8 ah[2];
        #pragma unroll
        for (int m=0;m<2;m++)
            ah[m] = *(const bf16x8*)(&aHi[mpair*32 + m*16 + fcol][0] + k8*32 + quad*8);
        #pragma unroll
        for (int t=0;t<3;t++){
            const int fi = (ngrp*3 + t)*3 + k8;
            const bf16x8 bh = *(const bf16x8*)(whi + (size_t)fi*512 + lane*8);
            #pragma unroll
            for (int m=0;m<2;m++)
                acc[m][t] = __builtin_amdgcn_mfma_f32_16x16x32_bf16(ah[m], bh, acc[m][t], 0, 0, 0);
        }
    }

    float bb[3];
    #pragma unroll
    for (int t=0;t<3;t++) bb[t] = (ncol[t] < C) ? b2[ncol[t]] : 0.0f;

    int dprev = dstS[ebase];
    float run[3] = {0.f,0.f,0.f};
    #pragma unroll
    for (int j=0;j<8;j++){
        const int d = dstS[ebase + j];
        if (d != dprev){
            #pragma unroll
            for (int t=0;t<3;t++){
                if (ncol[t] < C) atomicAdd(&agg92[(size_t)dprev*C + ncol[t]], run[t]);
                run[t] = 0.0f;
            }
            dprev = d;
        }
        #pragma unroll
        for (int t=0;t<3;t++)
            run[t] += (acc[j>>2][t][j&3] + bb[t]) * xv[j][t];
    }
    #pragma unroll
    for (int t=0;t<3;t++)
        if (ncol[t] < C) atomicAdd(&agg92[(size_t)dprev*C + ncol[t]], run[t]);
}

// ---------------------------------------------------------------- node update 92->256 MFMA; 2-MFMA scheme (A hi/lo x B-RNE); zeroes agg
__global__ __launch_bounds__(256) void node_update92_mfma_kernel(
    float* __restrict__ agg92,          // = agg + N*164 (aliased tail)
    float* __restrict__ aggfull,        // full [N,256] buffer, zero prefix [0, N*164)
    const unsigned short* __restrict__ whi,          // 48 frags
    const float* __restrict__ b, float* __restrict__ xout)
{
    constexpr int C = EMB_DIM;
    constexpr int KP = 96;
    constexpr int LDA = 104;
    __shared__ unsigned short aHi[16][LDA];
    __shared__ unsigned short aLo[16][LDA];

    const int n0  = blockIdx.x * 16;
    const int tid = threadIdx.x;

    for (int idx = tid; idx < 16*KP; idx += 256){
        const int i = idx / KP, k = idx - i*KP;
        const int node = n0 + i;
        float v = 0.0f;
        if (k < C && node < N_NODES){
            v = agg92[(size_t)node*C + k];
            agg92[(size_t)node*C + k] = 0.0f;
        }
        unsigned short hb, lb;
        split_bf(v, hb, lb);
        aHi[i][k] = hb;
        aLo[i][k] = lb;
    }
    __syncthreads();

    const int lane = tid & 63, wv = tid >> 6;
    const int quad = lane >> 4, fcol = lane & 15;

    f32x4 acc[4];
    #pragma unroll
    for (int t=0;t<4;t++)
        #pragma unroll
        for (int j=0;j<4;j++) acc[t][j] = 0.0f;

    const unsigned short* aHrow = &aHi[fcol][0];
    const unsigned short* aLrow = &aLo[fcol][0];

    for (int k8=0;k8<3;k8++){
        const bf16x8 ah = *(const bf16x8*)(aHrow + k8*32 + quad*8);
        const bf16x8 al = *(const bf16x8*)(aLrow + k8*32 + quad*8);
        #pragma unroll
        for (int t=0;t<4;t++){
            const int fi = (wv*4 + t)*3 + k8;
            const bf16x8 bh = *(const bf16x8*)(whi + (size_t)fi*512 + lane*8);
            acc[t] = __builtin_amdgcn_mfma_f32_16x16x32_bf16(ah, bh, acc[t], 0, 0, 0);
            acc[t] = __builtin_amdgcn_mfma_f32_16x16x32_bf16(al, bh, acc[t], 0, 0, 0);
        }
    }

    #pragma unroll
    for (int i=0;i<4;i++){
        const int node = n0 + quad*4 + i;
        if (node < N_NODES){
            #pragma unroll
            for (int t=0;t<4;t++){
                const int n = (wv*4 + t)*16 + fcol;
                xout[(size_t)node*HID + n] = softplusf(acc[t][i] + b[n]);
            }
        }
    }

    const int nth = gridDim.x*256;
    for (int idx = blockIdx.x*256 + tid; idx < N_NODES*164; idx += nth)
        aggfull[idx] = 0.0f;
}

// ---------------------------------------------------------------- layers 1-3 edge conv, MFMA, 64 edges/block, 512 threads (8 waves)
// R18 configuration (measured best): gathers issued in bulk AFTER the MFMA loop.
__global__ __launch_bounds__(512, 6) void edge_conv256_mfma_kernel(
    const int* __restrict__ src_s, const int* __restrict__ dst_s,
    const float* __restrict__ ea_s,
    const float* __restrict__ w1, const float* __restrict__ b1,
    const unsigned short* __restrict__ whi,
    const float* __restrict__ b2,
    const float* __restrict__ x, float* __restrict__ agg)
{
    constexpr int C = HID;
    constexpr int LDA = C + 8;                 // 528 B row stride
    constexpr int EPB = 64;
    constexpr int NWIN = (N_EDGES + EPB - 1) / EPB;   // 4688
    __shared__ unsigned short aHi[EPB][LDA];   // 33.8 KB
    __shared__ float eaS[EPB][4];
    __shared__ int   srcS[EPB];
    __shared__ int   dstS[EPB];

    const int win = xcd_window(NWIN);
    if (win < 0) return;
    const int e0  = win * EPB;
    const int tid = threadIdx.x;

    if (tid < 256){
        const int e = tid >> 2, comp = tid & 3;
        const int eid = min(e0 + e, N_EDGES-1);
        eaS[e][comp] = ea_s[(size_t)eid*4 + comp];
    } else if (tid < 320){
        const int e = tid - 256;
        srcS[e] = src_s[min(e0 + e, N_EDGES-1)];
    } else if (tid < 384){
        const int e = tid - 320;
        dstS[e] = dst_s[min(e0 + e, N_EDGES-1)];
    }
    __syncthreads();

    // phase 1: h1 = softplus(ea@w1+b1) -> bf16 LDS rows (chain-permuted), 2 channels/thread
    {
        const int k2 = (tid & 127) * 2;
        const int g  = tid >> 7;               // 0..3: edges [g*16, g*16+16)
        const float wa0 = w1[k2],   wa1 = w1[C+k2],   wa2 = w1[2*C+k2],   wa3 = w1[3*C+k2];
        const float wb0 = w1[k2+1], wb1 = w1[C+k2+1], wb2 = w1[2*C+k2+1], wb3 = w1[3*C+k2+1];
        const float bk0 = b1[k2], bk1 = b1[k2+1];
        #pragma unroll
        for (int ii=0; ii<16; ii++){
            const int e = g*16 + ii;
            const float4 a = *(const float4*)&eaS[e][0];
            const float v0 = fmaf(a.x,wa0,fmaf(a.y,wa1,fmaf(a.z,wa2,fmaf(a.w,wa3,bk0))));
            const float v1 = fmaf(a.x,wb0,fmaf(a.y,wb1,fmaf(a.z,wb2,fmaf(a.w,wb3,bk1))));
            const unsigned int packed = (unsigned int)f2bf_trunc(softplusf(v0))
                                      | ((unsigned int)f2bf_trunc(softplusf(v1)) << 16);
            const int q = e >> 4, j = e & 15;
            *(unsigned int*)&aHi[(j>>2)*16 + q*4 + (j&3)][k2] = packed;
        }
    }
    __syncthreads();

    const int lane = tid & 63, wv = tid >> 6;  // 8 waves
    const int quad = lane >> 4, fcol = lane & 15;

    f32x4 acc[4][2];     // [m-tile][n-tile]
    #pragma unroll
    for (int m=0;m<4;m++)
        #pragma unroll
        for (int t=0;t<2;t++)
            #pragma unroll
            for (int j=0;j<4;j++) acc[m][t][j] = 0.0f;

    for (int k8=0;k8<8;k8++){
        bf16x8 ah[4];
        #pragma unroll
        for (int m=0;m<4;m++)
            ah[m] = *(const bf16x8*)(&aHi[m*16 + fcol][0] + k8*32 + quad*8);
        #pragma unroll
        for (int t=0;t<2;t++){
            const int fi = (wv*2 + t)*8 + k8;
            const bf16x8 bh = *(const bf16x8*)(whi + (size_t)fi*512 + lane*8);
            #pragma unroll
            for (int m=0;m<4;m++)
                acc[m][t] = __builtin_amdgcn_mfma_f32_16x16x32_bf16(ah[m], bh, acc[m][t], 0, 0, 0);
        }
    }

    float bb[2];
    #pragma unroll
    for (int t=0;t<2;t++) bb[t] = b2[(wv*2 + t)*16 + fcol];

    const int ebase = quad*16;
    float xv[16][2];
    #pragma unroll
    for (int j=0;j<16;j++){
        const int s = srcS[ebase + j];
        const bool valid = (e0 + ebase + j) < N_EDGES;
        #pragma unroll
        for (int t=0;t<2;t++)
            xv[j][t] = valid ? x[(size_t)s*C + (wv*2 + t)*16 + fcol] : 0.0f;
    }

    int dprev = dstS[ebase];
    float run[2] = {0.f,0.f};
    #pragma unroll
    for (int j=0;j<16;j++){
        const int d = dstS[ebase + j];
        if (d != dprev){
            #pragma unroll
            for (int t=0;t<2;t++){
                atomicAdd(&agg[(size_t)dprev*C + (wv*2 + t)*16 + fcol], run[t]);
                run[t] = 0.0f;
            }
            dprev = d;
        }
        #pragma unroll
        for (int t=0;t<2;t++)
            run[t] += (acc[j>>2][t][j&3] + bb[t]) * xv[j][t];
    }
    #pragma unroll
    for (int t=0;t<2;t++)
        atomicAdd(&agg[(size_t)dprev*C + (wv*2 + t)*16 + fcol], run[t]);
}

// ---------------------------------------------------------------- node update MFMA (CIN=256); 2-MFMA scheme; optional zeroing; optional fused pool
__global__ __launch_bounds__(256) void node_update_mfma_kernel(
    float* __restrict__ agg,
    const unsigned short* __restrict__ whi,
    const float* __restrict__ b, float* __restrict__ xout, int zero_agg,
    const int* __restrict__ batch, float* __restrict__ sums, int do_pool)
{
    constexpr int C = HID;
    constexpr int LDA = C + 8;
    __shared__ unsigned short aHi[16][LDA];
    __shared__ unsigned short aLo[16][LDA];
    __shared__ int batchS[16];

    const int n0  = blockIdx.x * 16;
    const int tid = threadIdx.x;

    if (tid < 16) batchS[tid] = batch[min(n0 + tid, N_NODES-1)];

    #pragma unroll
    for (int it=0; it<16; it++){
        const int node = n0 + it;
        float v = 0.0f;
        if (node < N_NODES){
            v = agg[(size_t)node*C + tid];
            if (zero_agg) agg[(size_t)node*C + tid] = 0.0f;
        }
        unsigned short hb, lb;
        split_bf(v, hb, lb);
        aHi[it][tid] = hb;
        aLo[it][tid] = lb;
    }
    __syncthreads();

    const int lane = tid & 63, wv = tid >> 6;
    const int quad = lane >> 4, fcol = lane & 15;

    f32x4 acc[4];
    #pragma unroll
    for (int t=0;t<4;t++)
        #pragma unroll
        for (int j=0;j<4;j++) acc[t][j] = 0.0f;

    const unsigned short* aHrow = &aHi[fcol][0];
    const unsigned short* aLrow = &aLo[fcol][0];

    for (int k8=0;k8<8;k8++){
        const bf16x8 ah = *(const bf16x8*)(aHrow + k8*32 + quad*8);
        const bf16x8 al = *(const bf16x8*)(aLrow + k8*32 + quad*8);
        #pragma unroll
        for (int t=0;t<4;t++){
            const int fi = (wv*4 + t)*8 + k8;
            const bf16x8 bh = *(const bf16x8*)(whi + (size_t)fi*512 + lane*8);
            acc[t] = __builtin_amdgcn_mfma_f32_16x16x32_bf16(ah, bh, acc[t], 0, 0, 0);
            acc[t] = __builtin_amdgcn_mfma_f32_16x16x32_bf16(al, bh, acc[t], 0, 0, 0);
        }
    }

    float vals[4][4];
    #pragma unroll
    for (int i=0;i<4;i++){
        const int node = n0 + quad*4 + i;
        #pragma unroll
        for (int t=0;t<4;t++){
            float v = 0.0f;
            if (node < N_NODES){
                const int n = (wv*4 + t)*16 + fcol;
                v = softplusf(acc[t][i] + b[n]);
                xout[(size_t)node*C + n] = v;
            }
            vals[i][t] = v;
        }
    }

    if (do_pool){
        int gprev = batchS[quad*4];
        float run[4] = {0.f,0.f,0.f,0.f};
        #pragma unroll
        for (int i=0;i<4;i++){
            const int g = batchS[quad*4 + i];
            if (g != gprev){
                #pragma unroll
                for (int t=0;t<4;t++){
                    atomicAdd(&sums[(size_t)gprev*HID + (wv*4+t)*16 + fcol], run[t]);
                    run[t] = 0.0f;
                }
                gprev = g;
            }
            #pragma unroll
            for (int t=0;t<4;t++) run[t] += vals[i][t];
        }
        #pragma unroll
        for (int t=0;t<4;t++)
            atomicAdd(&sums[(size_t)gprev*HID + (wv*4+t)*16 + fcol], run[t]);
    }
}

// ---------------------------------------------------------------- readout MLP (one block per graph)
__global__ __launch_bounds__(256) void readout_kernel(
    const float* __restrict__ sums, const int* __restrict__ gcnt,
    const float* __restrict__ rw1, const float* __restrict__ rb1,
    const float* __restrict__ rw2, const float* __restrict__ rb2,
    const float* __restrict__ rw3, const float* __restrict__ rb3,
    float* __restrict__ out)
{
    __shared__ float g[HID];
    __shared__ float h[HID];
    __shared__ float h2[HID/2];
    __shared__ float red[256];
    const int gi = blockIdx.x;
    const int t  = threadIdx.x;
    const float cnt = fmaxf((float)gcnt[gi], 1.0f);
    g[t] = sums[(size_t)gi*HID + t] / cnt;
    __syncthreads();
    float acc = rb1[t];
    for (int k=0;k<HID;k++) acc = fmaf(g[k], rw1[(size_t)k*HID + t], acc);
    h[t] = softplusf(acc);
    __syncthreads();
    if (t < HID/2){
        float a2 = rb2[t];
        for (int k=0;k<HID;k++) a2 = fmaf(h[k], rw2[(size_t)k*(HID/2) + t], a2);
        h2[t] = softplusf(a2);
    }
    __syncthreads();
    red[t] = (t < HID/2) ? h2[t]*rw3[t] : 0.0f;
    __syncthreads();
    for (int s2=128; s2>0; s2>>=1){
        if (t < s2) red[t] += red[t+s2];
        __syncthreads();
    }
    if (t == 0) out[gi] = red[0] + rb3[0];
}

// ---------------------------------------------------------------- launcher
extern "C" void kernel_launch(void* const* d_in, const int* in_sizes, int n_in,
                              void* d_out, int out_size, void* d_ws, size_t ws_size,
                              hipStream_t stream)
{
    const int*   x_atoms = (const int*)d_in[0];
    const int*   eidx    = (const int*)d_in[1];
    const int*   src     = eidx;               // edge_index[0]
    const int*   dst     = eidx + N_EDGES;     // edge_index[1]
    const float* ea      = (const float*)d_in[2];
    const int*   batch   = (const int*)d_in[3];
    const float* emb     = (const float*)d_in[4];
    const float* ew1_0   = (const float*)d_in[5];
    const float* eb1_0   = (const float*)d_in[6];
    const float* ew2_0   = (const float*)d_in[7];
    const float* eb2_0   = (const float*)d_in[8];
    const float* nw_0    = (const float*)d_in[9];
    const float* nb_0    = (const float*)d_in[10];
    const float* ew1     = (const float*)d_in[11];
    const float* eb1     = (const float*)d_in[12];
    const float* ew2     = (const float*)d_in[13];
    const float* eb2     = (const float*)d_in[14];
    const float* nw      = (const float*)d_in[15];
    const float* nb      = (const float*)d_in[16];
    const float* rw1     = (const float*)d_in[17];
    const float* rb1     = (const float*)d_in[18];
    const float* rw2     = (const float*)d_in[19];
    const float* rb2     = (const float*)d_in[20];
    const float* rw3     = (const float*)d_in[21];
    const float* rb3     = (const float*)d_in[22];
    float* out = (float*)d_out;

    float* x    = (float*)d_ws;
    float* agg  = x   + (size_t)N_NODES*HID;
    float* agg92 = agg + (size_t)N_NODES*164;          // aliased tail of agg ([N,92] region)
    float* sums = agg + (size_t)N_NODES*HID;
    unsigned short* whi  = (unsigned short*)(sums + (size_t)N_GRAPHS*HID);
    unsigned short* nwhi = whi  + (size_t)3*128*512;
    unsigned short* w92hi  = nwhi + (size_t)3*128*512;    // 18 frags
    unsigned short* nw92hi = w92hi + (size_t)18*512;      // 48 frags
    float* ea_s = (float*)(nw92hi + (size_t)48*512);      // [E,4] sorted edge attrs
    int* hist   = (int*)(ea_s + (size_t)N_EDGES*4);
    int* gcnt   = hist   + N_NODES;                       // [256] graph sizes
    int* cursor = gcnt   + N_GRAPHS;
    int* src_s  = cursor + N_NODES;
    int* dst_s  = src_s  + N_EDGES;

    const int NWIN64 = (N_EDGES + 63) / 64;           // 4688 (divisible by 8)

    // 1. embedding gather + zero hist/gcnt/sums
    hipLaunchKernelGGL(gather_emb_kernel, dim3(N_NODES), dim3(128), 0, stream,
                       x_atoms, emb, x, hist, gcnt, sums);
    // 2-4. counting sort by dst (+ graph sizes, + zero agg92 region)
    hipLaunchKernelGGL(hist_kernel, dim3((N_EDGES+255)/256), dim3(256), 0, stream, dst, hist, batch, gcnt);
    hipLaunchKernelGGL(scan_kernel, dim3(1), dim3(1024), 0, stream, hist, cursor);
    hipLaunchKernelGGL(scatter_kernel, dim3((N_EDGES+255)/256), dim3(256), 0, stream,
                       src, dst, ea, cursor, src_s, dst_s, ea_s, agg92);
    // 5. pack all weights (hi only — 2-MFMA schemes everywhere)
    hipLaunchKernelGGL(pack_all_kernel, dim3(834), dim3(256), 0, stream,
                       ew2, nw, ew2_0, nw_0,
                       whi, nwhi, w92hi, nw92hi);

    // 6-7. layer 0
    hipLaunchKernelGGL(edge_conv92_mfma_kernel, dim3((NWIN64+7)/8*8), dim3(256), 0, stream,
                       src_s, dst_s, ea_s, ew1_0, eb1_0, w92hi, eb2_0, x, agg92);
    hipLaunchKernelGGL(node_update92_mfma_kernel, dim3((N_NODES+15)/16), dim3(256), 0, stream,
                       agg92, agg, nw92hi, nb_0, x);

    // 8-10. layers 1..3
    for (int i=0;i<3;i++){
        hipLaunchKernelGGL(edge_conv256_mfma_kernel, dim3((NWIN64+7)/8*8), dim3(512), 0, stream,
                           src_s, dst_s, ea_s,
                           ew1 + (size_t)i*4*HID, eb1 + (size_t)i*HID,
                           whi + (size_t)i*128*512,
                           eb2 + (size_t)i*HID,
                           x, agg);
        hipLaunchKernelGGL(node_update_mfma_kernel, dim3((N_NODES+15)/16), dim3(256), 0, stream,
                           agg, nwhi + (size_t)i*128*512,
                           nb + (size_t)i*HID, x, (i < 2) ? 1 : 0,
                           batch, sums, (i == 2) ? 1 : 0);
    }

    // 11. readout
    hipLaunchKernelGGL(readout_kernel, dim3(N_GRAPHS), dim3(256), 0, stream,
                       sums, gcnt, rw1, rb1, rw2, rb2, rw3, rb3, out);
}